// Round 1
// baseline (221.685 us; speedup 1.0000x reference)
//
#include <hip/hip_runtime.h>
#include <hip/hip_bf16.h>
#include <math.h>

#define BROWS 4096
#define NCOLS 8192
#define LLEN  256
#define EPSV  1e-8f

__global__ void zero_out_kernel(float* out) { out[0] = 0.0f; }

__global__ __launch_bounds__(256) void listmle_kernel(
    const float* __restrict__ logits,
    const int*   __restrict__ ids,
    const float* __restrict__ weights,
    float*       __restrict__ out)
{
    __shared__ float s_g[LLEN];
    __shared__ unsigned long long s_key[LLEN];
    __shared__ float s_m[LLEN];
    __shared__ float s_s[LLEN];
    __shared__ float s_red[4];

    const int tid = threadIdx.x;
    const int b   = blockIdx.x;

    // ---- load: weight, id, gathered logit ----
    float w  = weights[(size_t)b * LLEN + tid];
    int   id = ids[(size_t)b * LLEN + tid];
    float g  = logits[(size_t)b * NCOLS + id];

    s_g[tid] = g;
    // sort key: descending weight, ties -> ascending original position (JAX stable argsort)
    // w in [0,1): float bits are order-monotone for non-negative floats
    s_key[tid] = ((unsigned long long)__float_as_uint(w) << 32)
               | (unsigned)(LLEN - 1 - tid);

    // ---- weight sum (wave64 shuffle + cross-wave LDS) ----
    float v = w;
    #pragma unroll
    for (int o = 32; o > 0; o >>= 1) v += __shfl_down(v, o);
    if ((tid & 63) == 0) s_red[tid >> 6] = v;
    __syncthreads();
    float wsum = s_red[0] + s_red[1] + s_red[2] + s_red[3];

    // ---- bitonic sort, descending by u64 key ----
    for (int k = 2; k <= LLEN; k <<= 1) {
        for (int j = k >> 1; j > 0; j >>= 1) {
            int ixj = tid ^ j;
            if (ixj > tid) {
                unsigned long long a = s_key[tid];
                unsigned long long c = s_key[ixj];
                bool up = ((tid & k) == 0);
                // descending sort: swap when (a < c) in "up" blocks
                if ((a < c) == up) { s_key[tid] = c; s_key[ixj] = a; }
            }
            __syncthreads();
        }
    }

    unsigned long long key = s_key[tid];
    float ow  = __uint_as_float((unsigned)(key >> 32));   // ordered weight (unnormalized)
    int   pos = (LLEN - 1) - (int)(key & 0xFFFFFFFFull);  // original position
    float og  = s_g[pos];                                  // ordered logit

    // ---- reverse inclusive logsumexp scan (Hillis-Steele, (m,s) pairs) ----
    float m = og, ssum = 1.0f;
    s_m[tid] = m; s_s[tid] = ssum;
    __syncthreads();
    #pragma unroll
    for (int off = 1; off < LLEN; off <<= 1) {
        float mp = 0.0f, sp = 0.0f;
        bool has = (tid + off) < LLEN;
        if (has) { mp = s_m[tid + off]; sp = s_s[tid + off]; }
        __syncthreads();
        if (has) {
            float nm = fmaxf(m, mp);
            ssum = ssum * expf(m - nm) + sp * expf(mp - nm);
            m = nm;
            s_m[tid] = m; s_s[tid] = ssum;
        }
        __syncthreads();
    }
    float suffix_lse = m + logf(ssum);

    // ---- weighted term + block reduce ----
    float t = ow * (suffix_lse - og);
    #pragma unroll
    for (int o = 32; o > 0; o >>= 1) t += __shfl_down(t, o);
    if ((tid & 63) == 0) s_red[tid >> 6] = t;
    __syncthreads();

    if (tid == 0) {
        float tot  = s_red[0] + s_red[1] + s_red[2] + s_red[3];
        float loss = tot / fmaxf(wsum, EPSV);
        atomicAdd(out, loss * (1.0f / (float)BROWS));
    }
}

extern "C" void kernel_launch(void* const* d_in, const int* in_sizes, int n_in,
                              void* d_out, int out_size, void* d_ws, size_t ws_size,
                              hipStream_t stream) {
    const float* logits  = (const float*)d_in[0];
    const int*   ids     = (const int*)d_in[1];
    const float* weights = (const float*)d_in[2];
    float* out = (float*)d_out;

    zero_out_kernel<<<dim3(1), dim3(1), 0, stream>>>(out);
    listmle_kernel<<<dim3(BROWS), dim3(LLEN), 0, stream>>>(logits, ids, weights, out);
}

// Round 2
// 220.679 us; speedup vs baseline: 1.0046x; 1.0046x over previous
//
#include <hip/hip_runtime.h>
#include <hip/hip_bf16.h>
#include <math.h>

#define BROWS 4096
#define NCOLS 8192
#define LLEN  256
#define EPSV  1e-8f

__global__ void zero_out_kernel(float* out) { out[0] = 0.0f; }

__global__ __launch_bounds__(256) void listmle_kernel(
    const float* __restrict__ logits,
    const int*   __restrict__ ids,
    const float* __restrict__ weights,
    float*       __restrict__ out)
{
    __shared__ float s_g[LLEN];
    __shared__ unsigned long long s_key[2][LLEN];  // double-buffered for 1-barrier steps
    __shared__ float s_aggm[4], s_aggs[4];
    __shared__ float s_redt[4], s_redw[4];

    const int tid  = threadIdx.x;
    const int lane = tid & 63;
    const int wv   = tid >> 6;
    const int b    = blockIdx.x;

    // ---- load: weight, id, gathered logit ----
    float w  = weights[(size_t)b * LLEN + tid];
    int   id = ids[(size_t)b * LLEN + tid];
    float g  = logits[(size_t)b * NCOLS + id];
    s_g[tid] = g;

    // sort key: descending weight, ties -> ascending original position (stable argsort).
    // w in [0,1): float bits are order-monotone for non-negative floats.
    unsigned key_hi = __float_as_uint(w);
    unsigned key_lo = (unsigned)(LLEN - 1 - tid);

    // ---- bitonic sort, descending, one element/thread ----
    // j < 64  -> intra-wave compare-exchange via shfl_xor (no barriers, no divergence)
    // j >= 64 -> LDS exchange, double-buffered (1 barrier each; only 3 such steps)
    int phase = 0;
    #pragma unroll
    for (int k = 2; k <= LLEN; k <<= 1) {
        #pragma unroll
        for (int j = k >> 1; j > 0; j >>= 1) {
            const bool keep_max = (((tid & k) == 0) == ((tid & j) == 0));
            unsigned p_hi, p_lo;
            if (j < 64) {
                p_hi = __shfl_xor(key_hi, j);
                p_lo = __shfl_xor(key_lo, j);
            } else {
                s_key[phase][tid] = ((unsigned long long)key_hi << 32) | key_lo;
                __syncthreads();
                unsigned long long p = s_key[phase][tid ^ j];
                p_hi = (unsigned)(p >> 32);
                p_lo = (unsigned)p;
                phase ^= 1;
            }
            const bool pgt  = (p_hi > key_hi) || (p_hi == key_hi && p_lo > key_lo);
            if (pgt == keep_max) { key_hi = p_hi; key_lo = p_lo; }
        }
    }

    float ow  = __uint_as_float(key_hi);          // ordered (unnormalized) weight
    int   pos = (LLEN - 1) - (int)key_lo;         // original position
    float og  = s_g[pos];                         // ordered logit (sort barriers fence the write)

    // ---- reverse inclusive logsumexp scan over tid=0..255 ----
    // intra-wave reverse scan via shfl_down: lane i gets combine of [i..63]
    float m = og, s = 1.0f;
    #pragma unroll
    for (int off = 1; off < 64; off <<= 1) {
        float mp = __shfl_down(m, off);
        float sp = __shfl_down(s, off);
        if (lane + off < 64) {
            float nm = fmaxf(m, mp);
            s = s * __expf(m - nm) + sp * __expf(mp - nm);
            m = nm;
        }
    }
    // cross-wave: wave w folds in aggregates (lane-0 values) of waves w+1..3
    if (lane == 0) { s_aggm[wv] = m; s_aggs[wv] = s; }
    __syncthreads();
    #pragma unroll
    for (int w2 = 0; w2 < 4; ++w2) {
        if (w2 > wv) {
            float mp = s_aggm[w2], sp = s_aggs[w2];
            float nm = fmaxf(m, mp);
            s = s * __expf(m - nm) + sp * __expf(mp - nm);
            m = nm;
        }
    }
    float suffix_lse = m + logf(s);

    // ---- weighted term + weight sum, fused block reduce ----
    float t  = ow * (suffix_lse - og);
    float ws = ow;   // sum of sorted weights == sum of weights
    #pragma unroll
    for (int o = 32; o > 0; o >>= 1) {
        t  += __shfl_down(t, o);
        ws += __shfl_down(ws, o);
    }
    if (lane == 0) { s_redt[wv] = t; s_redw[wv] = ws; }
    __syncthreads();
    if (tid == 0) {
        float tot  = s_redt[0] + s_redt[1] + s_redt[2] + s_redt[3];
        float wsum = s_redw[0] + s_redw[1] + s_redw[2] + s_redw[3];
        float loss = tot / fmaxf(wsum, EPSV);
        atomicAdd(out, loss * (1.0f / (float)BROWS));
    }
}

extern "C" void kernel_launch(void* const* d_in, const int* in_sizes, int n_in,
                              void* d_out, int out_size, void* d_ws, size_t ws_size,
                              hipStream_t stream) {
    const float* logits  = (const float*)d_in[0];
    const int*   ids     = (const int*)d_in[1];
    const float* weights = (const float*)d_in[2];
    float* out = (float*)d_out;

    zero_out_kernel<<<dim3(1), dim3(1), 0, stream>>>(out);
    listmle_kernel<<<dim3(BROWS), dim3(LLEN), 0, stream>>>(logits, ids, weights, out);
}

// Round 3
// 189.480 us; speedup vs baseline: 1.1700x; 1.1647x over previous
//
#include <hip/hip_runtime.h>
#include <hip/hip_bf16.h>
#include <math.h>

#define BROWS 4096
#define NCOLS 8192
#define LLEN  256
#define EPSV  1e-8f

__global__ __launch_bounds__(256) void listmle_kernel(
    const float* __restrict__ logits,
    const int*   __restrict__ ids,
    const float* __restrict__ weights,
    float*       __restrict__ partial)
{
    __shared__ float s_g[LLEN];
    __shared__ unsigned long long s_key[2][LLEN];  // double-buffered cross-wave exchange
    __shared__ float s_aggm[4], s_aggs[4];
    __shared__ float s_redt[4], s_redw[4];

    const int tid  = threadIdx.x;
    const int lane = tid & 63;
    const int wv   = tid >> 6;
    const int b    = blockIdx.x;

    // ---- loads. The gather g is long-latency (random in row); its first use
    // is deferred until after the intra-wave sort stages so shuffles hide it.
    float w  = weights[(size_t)b * LLEN + tid];
    int   id = ids[(size_t)b * LLEN + tid];
    float g  = logits[(size_t)b * NCOLS + id];

    // sort key: descending weight, ties -> ascending original position (stable argsort).
    // w in [0,1): float bits are order-monotone for non-negative floats.
    unsigned key_hi = __float_as_uint(w);
    unsigned key_lo = (unsigned)(LLEN - 1 - tid);

    // ---- bitonic sort stages k=2..64: purely intra-wave (shfl_xor, no barriers).
    // These depend only on w, NOT on g -> they overlap the gather's latency.
    #pragma unroll
    for (int k = 2; k <= 64; k <<= 1) {
        #pragma unroll
        for (int j = k >> 1; j > 0; j >>= 1) {
            const bool keep_max = (((tid & k) == 0) == ((tid & j) == 0));
            unsigned p_hi = __shfl_xor(key_hi, j);
            unsigned p_lo = __shfl_xor(key_lo, j);
            const bool pgt = (p_hi > key_hi) || (p_hi == key_hi && p_lo > key_lo);
            if (pgt == keep_max) { key_hi = p_hi; key_lo = p_lo; }
        }
    }

    // first (and only) consumption of g before the sort's first barrier:
    // the vmcnt wait lands here, ~21 shuffle steps after issue.
    s_g[tid] = g;

    // ---- stages k=128,256: j>=64 exchanges via double-buffered LDS (3 barriers total)
    int phase = 0;
    #pragma unroll
    for (int k = 128; k <= LLEN; k <<= 1) {
        #pragma unroll
        for (int j = k >> 1; j > 0; j >>= 1) {
            const bool keep_max = (((tid & k) == 0) == ((tid & j) == 0));
            unsigned p_hi, p_lo;
            if (j >= 64) {
                s_key[phase][tid] = ((unsigned long long)key_hi << 32) | key_lo;
                __syncthreads();
                unsigned long long p = s_key[phase][tid ^ j];
                p_hi = (unsigned)(p >> 32);
                p_lo = (unsigned)p;
                phase ^= 1;
            } else {
                p_hi = __shfl_xor(key_hi, j);
                p_lo = __shfl_xor(key_lo, j);
            }
            const bool pgt = (p_hi > key_hi) || (p_hi == key_hi && p_lo > key_lo);
            if (pgt == keep_max) { key_hi = p_hi; key_lo = p_lo; }
        }
    }

    float ow  = __uint_as_float(key_hi);          // ordered (unnormalized) weight
    int   pos = (LLEN - 1) - (int)key_lo;         // original position
    float og  = s_g[pos];                         // s_g writes fenced by sort barriers

    // ---- reverse inclusive logsumexp scan over tid=0..255 ----
    float m = og, s = 1.0f;
    #pragma unroll
    for (int off = 1; off < 64; off <<= 1) {
        float mp = __shfl_down(m, off);
        float sp = __shfl_down(s, off);
        if (lane + off < 64) {
            float nm = fmaxf(m, mp);
            s = s * __expf(m - nm) + sp * __expf(mp - nm);
            m = nm;
        }
    }
    if (lane == 0) { s_aggm[wv] = m; s_aggs[wv] = s; }
    __syncthreads();
    #pragma unroll
    for (int w2 = 0; w2 < 4; ++w2) {
        if (w2 > wv) {
            float mp = s_aggm[w2], sp = s_aggs[w2];
            float nm = fmaxf(m, mp);
            s = s * __expf(m - nm) + sp * __expf(mp - nm);
            m = nm;
        }
    }
    float suffix_lse = m + logf(s);

    // ---- weighted term + weight sum, fused block reduce ----
    float t  = ow * (suffix_lse - og);
    float ws = ow;   // sum of sorted weights == sum of weights
    #pragma unroll
    for (int o = 32; o > 0; o >>= 1) {
        t  += __shfl_down(t, o);
        ws += __shfl_down(ws, o);
    }
    if (lane == 0) { s_redt[wv] = t; s_redw[wv] = ws; }
    __syncthreads();
    if (tid == 0) {
        float tot  = s_redt[0] + s_redt[1] + s_redt[2] + s_redt[3];
        float wsum = s_redw[0] + s_redw[1] + s_redw[2] + s_redw[3];
        partial[b] = tot / fmaxf(wsum, EPSV);     // no atomics: per-block partial
    }
}

__global__ __launch_bounds__(256) void reduce_kernel(
    const float* __restrict__ partial, float* __restrict__ out)
{
    __shared__ float s_red[4];
    const int tid  = threadIdx.x;
    const int lane = tid & 63;
    const int wv   = tid >> 6;

    float v = 0.0f;
    #pragma unroll
    for (int i = 0; i < BROWS / 256; ++i)
        v += partial[i * 256 + tid];

    #pragma unroll
    for (int o = 32; o > 0; o >>= 1) v += __shfl_down(v, o);
    if (lane == 0) s_red[wv] = v;
    __syncthreads();
    if (tid == 0)
        out[0] = (s_red[0] + s_red[1] + s_red[2] + s_red[3]) * (1.0f / (float)BROWS);
}

extern "C" void kernel_launch(void* const* d_in, const int* in_sizes, int n_in,
                              void* d_out, int out_size, void* d_ws, size_t ws_size,
                              hipStream_t stream) {
    const float* logits  = (const float*)d_in[0];
    const int*   ids     = (const int*)d_in[1];
    const float* weights = (const float*)d_in[2];
    float* out     = (float*)d_out;
    float* partial = (float*)d_ws;   // 4096 floats of scratch

    listmle_kernel<<<dim3(BROWS), dim3(LLEN), 0, stream>>>(logits, ids, weights, partial);
    reduce_kernel<<<dim3(1), dim3(256), 0, stream>>>(partial, out);
}

// Round 4
// 188.611 us; speedup vs baseline: 1.1754x; 1.0046x over previous
//
#include <hip/hip_runtime.h>
#include <hip/hip_bf16.h>
#include <math.h>

#define BROWS 4096
#define NCOLS 8192
#define LLEN  256
#define EPSV  1e-8f

__global__ __launch_bounds__(256) void listmle_kernel(
    const float* __restrict__ logits,
    const int*   __restrict__ ids,
    const float* __restrict__ weights,
    float*       __restrict__ partial)
{
    __shared__ float    s_g[LLEN];
    __shared__ float    s_w[LLEN];
    __shared__ unsigned s_key[2][LLEN];   // double-buffered cross-wave exchange
    __shared__ float    s_aggm[4], s_aggs[4];
    __shared__ float    s_redt[4], s_redw[4];

    const int tid  = threadIdx.x;
    const int lane = tid & 63;
    const int wv   = tid >> 6;
    const int b    = blockIdx.x;

    // ---- loads. Gather g is long-latency (random within a 32KB row); its
    // first use is deferred past the intra-wave sort so shuffles hide it.
    float w  = weights[(size_t)b * LLEN + tid];
    int   id = ids[(size_t)b * LLEN + tid];
    float g  = logits[(size_t)b * NCOLS + id];

    // Single 32-bit sort key: w in [0,1) => float bits < 2^30, order-monotone.
    // Top 24 bits of w_bits (22 mantissa bits kept) | 8-bit reversed position.
    // Descending sort => descending weight; truncated ties => ascending tid
    // (matches stable argsort; sub-2^-22 weight pairs may swap: ~1e-6 impact).
    unsigned key = (__float_as_uint(w) & 0xFFFFFF00u) | (unsigned)(LLEN - 1 - tid);

    // ---- bitonic sort stages k=2..64: intra-wave shfl_xor, 1 shuffle/step,
    // compare-exchange = max/min/select. Depends only on w -> overlaps gather.
    #pragma unroll
    for (int k = 2; k <= 64; k <<= 1) {
        #pragma unroll
        for (int j = k >> 1; j > 0; j >>= 1) {
            const bool keep_max = (((tid & k) == 0) == ((tid & j) == 0));
            unsigned p  = __shfl_xor(key, j);
            unsigned mx = key > p ? key : p;
            unsigned mn = key > p ? p : key;
            key = keep_max ? mx : mn;
        }
    }

    // first consumption of g / w before the sort's first barrier:
    // vmcnt wait lands here, ~20 shuffle steps after issue.
    s_g[tid] = g;
    s_w[tid] = w;

    // ---- stages k=128,256: j>=64 via double-buffered LDS (3 barriers total)
    int phase = 0;
    #pragma unroll
    for (int k = 128; k <= LLEN; k <<= 1) {
        #pragma unroll
        for (int j = k >> 1; j > 0; j >>= 1) {
            const bool keep_max = (((tid & k) == 0) == ((tid & j) == 0));
            unsigned p;
            if (j >= 64) {
                s_key[phase][tid] = key;
                __syncthreads();
                p = s_key[phase][tid ^ j];
                phase ^= 1;
            } else {
                p = __shfl_xor(key, j);
            }
            unsigned mx = key > p ? key : p;
            unsigned mn = key > p ? p : key;
            key = keep_max ? mx : mn;
        }
    }

    const int pos = (LLEN - 1) - (int)(key & 0xFFu);  // original position
    float og = s_g[pos];                              // ordered logit
    float ow = s_w[pos];                              // ordered full-precision weight

    // ---- reverse inclusive logsumexp scan over tid=0..255 ----
    float m = og, s = 1.0f;
    #pragma unroll
    for (int off = 1; off < 64; off <<= 1) {
        float mp = __shfl_down(m, off);
        float sp = __shfl_down(s, off);
        if (lane + off < 64) {
            float nm = fmaxf(m, mp);
            s = s * __expf(m - nm) + sp * __expf(mp - nm);
            m = nm;
        }
    }
    if (lane == 0) { s_aggm[wv] = m; s_aggs[wv] = s; }
    __syncthreads();
    #pragma unroll
    for (int w2 = 0; w2 < 4; ++w2) {
        if (w2 > wv) {
            float mp = s_aggm[w2], sp = s_aggs[w2];
            float nm = fmaxf(m, mp);
            s = s * __expf(m - nm) + sp * __expf(mp - nm);
            m = nm;
        }
    }
    float suffix_lse = m + __logf(s);

    // ---- weighted term + weight sum, fused block reduce ----
    float t  = ow * (suffix_lse - og);
    float ws = ow;   // sum of sorted weights == sum of weights
    #pragma unroll
    for (int o = 32; o > 0; o >>= 1) {
        t  += __shfl_down(t, o);
        ws += __shfl_down(ws, o);
    }
    if (lane == 0) { s_redt[wv] = t; s_redw[wv] = ws; }
    __syncthreads();
    if (tid == 0) {
        float tot  = s_redt[0] + s_redt[1] + s_redt[2] + s_redt[3];
        float wsum = s_redw[0] + s_redw[1] + s_redw[2] + s_redw[3];
        partial[b] = tot / fmaxf(wsum, EPSV);
    }
}

__global__ __launch_bounds__(256) void reduce_kernel(
    const float* __restrict__ partial, float* __restrict__ out)
{
    __shared__ float s_red[4];
    const int tid  = threadIdx.x;
    const int lane = tid & 63;
    const int wv   = tid >> 6;

    float v = 0.0f;
    #pragma unroll
    for (int i = 0; i < BROWS / 256; ++i)
        v += partial[i * 256 + tid];

    #pragma unroll
    for (int o = 32; o > 0; o >>= 1) v += __shfl_down(v, o);
    if (lane == 0) s_red[wv] = v;
    __syncthreads();
    if (tid == 0)
        out[0] = (s_red[0] + s_red[1] + s_red[2] + s_red[3]) * (1.0f / (float)BROWS);
}

extern "C" void kernel_launch(void* const* d_in, const int* in_sizes, int n_in,
                              void* d_out, int out_size, void* d_ws, size_t ws_size,
                              hipStream_t stream) {
    const float* logits  = (const float*)d_in[0];
    const int*   ids     = (const int*)d_in[1];
    const float* weights = (const float*)d_in[2];
    float* out     = (float*)d_out;
    float* partial = (float*)d_ws;   // 4096 floats of scratch

    listmle_kernel<<<dim3(BROWS), dim3(LLEN), 0, stream>>>(logits, ids, weights, partial);
    reduce_kernel<<<dim3(1), dim3(256), 0, stream>>>(partial, out);
}